// Round 1
// baseline (308.177 us; speedup 1.0000x reference)
//
#include <hip/hip_runtime.h>
#include <float.h>

// HierarchicalLoss: total = 0.5*sum_l CE(out_l, targets[:,l]) + 0.5*sum_l (e-1)*mean(1-V_l[p_l,p_{l+1}])
// Memory-bound on the 178 MB logit read; single-pass online logsumexp.

#define NB 4096

static constexpr float LOG2E = 1.4426950408889634f;
static constexpr float LN2   = 0.6931471805599453f;
static constexpr float E_M1  = 1.7182818284590452f;   // e - 1

__device__ __forceinline__ void combine_ms(float& m, float& s, float m2, float s2) {
    float mn = fmaxf(m, m2);
    s = s * exp2f((m - mn) * LOG2E) + s2 * exp2f((m2 - mn) * LOG2E);
    m = mn;
}

// One block (256 threads) per (level,row). Level 3 (C=8192) blocks first for tail balance.
__global__ __launch_bounds__(256) void ce_rows_kernel(
    const float* __restrict__ o0, const float* __restrict__ o1,
    const float* __restrict__ o2, const float* __restrict__ o3,
    const int* __restrict__ targets, float* __restrict__ nll)
{
    const int bid = blockIdx.x;
    const int lvl = 3 - (bid >> 12);          // 3,2,1,0
    const int row = bid & (NB - 1);

    const float* base; int C;
    if      (lvl == 0) { base = o0; C = 128;  }
    else if (lvl == 1) { base = o1; C = 512;  }
    else if (lvl == 2) { base = o2; C = 2048; }
    else               { base = o3; C = 8192; }

    const float4* rowp = (const float4*)(base + (size_t)row * C);
    const int C4 = C >> 2;

    // online (max, sum-exp): robust to any logit magnitude, single HBM pass
    float m = -FLT_MAX, s = 0.0f;
    for (int f = threadIdx.x; f < C4; f += 256) {
        float4 v = rowp[f];
        float m4 = fmaxf(fmaxf(v.x, v.y), fmaxf(v.z, v.w));
        float mn = fmaxf(m, m4);
        s = s * exp2f((m - mn) * LOG2E)
          + exp2f((v.x - mn) * LOG2E) + exp2f((v.y - mn) * LOG2E)
          + exp2f((v.z - mn) * LOG2E) + exp2f((v.w - mn) * LOG2E);
        m = mn;
    }

    // wave (64-lane) butterfly reduce of (m,s)
    #pragma unroll
    for (int off = 32; off; off >>= 1)
        combine_ms(m, s, __shfl_xor(m, off), __shfl_xor(s, off));

    __shared__ float lm[4], ls[4];
    const int wv = threadIdx.x >> 6;
    if ((threadIdx.x & 63) == 0) { lm[wv] = m; ls[wv] = s; }
    __syncthreads();

    if (threadIdx.x == 0) {
        float M = lm[0], S = ls[0];
        #pragma unroll
        for (int w = 1; w < 4; w++) combine_ms(M, S, lm[w], ls[w]);
        const int t  = targets[row * 4 + lvl];
        const float xt = base[(size_t)row * C + t];
        nll[lvl * NB + row] = M + log2f(S) * LN2 - xt;   // lse - x_target
    }
}

// Single block: reduce 4x4096 NLLs + 3x4096 validity gathers -> 3 scalars.
__global__ __launch_bounds__(1024) void finalize_kernel(
    const float* __restrict__ nll,
    const int* __restrict__ p0, const int* __restrict__ p1,
    const int* __restrict__ p2, const int* __restrict__ p3,
    const int* __restrict__ v01, const int* __restrict__ v12,
    const int* __restrict__ v23, float* __restrict__ out)
{
    const int tid = threadIdx.x;

    float ce[4] = {0.f, 0.f, 0.f, 0.f};
    #pragma unroll
    for (int l = 0; l < 4; l++)
        for (int i = tid; i < NB; i += 1024)
            ce[l] += nll[l * NB + i];

    float ok[3] = {0.f, 0.f, 0.f};
    for (int i = tid; i < NB; i += 1024) {
        const int a = p0[i], b = p1[i], c = p2[i], d = p3[i];
        ok[0] += (v01[a * 512  + b] != 0) ? 1.f : 0.f;
        ok[1] += (v12[b * 2048 + c] != 0) ? 1.f : 0.f;
        ok[2] += (v23[c * 8192 + d] != 0) ? 1.f : 0.f;
    }

    __shared__ float lds[16];
    float vals[7] = {ce[0], ce[1], ce[2], ce[3], ok[0], ok[1], ok[2]};
    float res[7];
    #pragma unroll
    for (int q = 0; q < 7; q++) {
        float v = vals[q];
        #pragma unroll
        for (int off = 32; off; off >>= 1) v += __shfl_xor(v, off);
        if ((tid & 63) == 0) lds[tid >> 6] = v;
        __syncthreads();
        if (tid == 0) {
            float t = 0.f;
            #pragma unroll
            for (int w = 0; w < 16; w++) t += lds[w];
            res[q] = t;
        }
        __syncthreads();
    }

    if (tid == 0) {
        const float inv_b = 1.0f / (float)NB;
        float total_ce = (res[0] + res[1] + res[2] + res[3]) * inv_b;
        float total_dep = 0.f;
        #pragma unroll
        for (int q = 4; q < 7; q++)
            total_dep += E_M1 * (((float)NB - res[q]) * inv_b);
        out[0] = 0.5f * total_ce + 0.5f * total_dep;  // ALPHA = 0.5
        out[1] = total_ce;
        out[2] = total_dep;
    }
}

extern "C" void kernel_launch(void* const* d_in, const int* in_sizes, int n_in,
                              void* d_out, int out_size, void* d_ws, size_t ws_size,
                              hipStream_t stream)
{
    const float* o0 = (const float*)d_in[0];   // 4096x128
    const float* o1 = (const float*)d_in[1];   // 4096x512
    const float* o2 = (const float*)d_in[2];   // 4096x2048
    const float* o3 = (const float*)d_in[3];   // 4096x8192
    const int* targets = (const int*)d_in[4];  // 4096x4
    const int* p0 = (const int*)d_in[5];
    const int* p1 = (const int*)d_in[6];
    const int* p2 = (const int*)d_in[7];
    const int* p3 = (const int*)d_in[8];
    const int* v01 = (const int*)d_in[9];      // 128x512
    const int* v12 = (const int*)d_in[10];     // 512x2048
    const int* v23 = (const int*)d_in[11];     // 2048x8192

    float* nll = (float*)d_ws;                 // 4*4096 floats, fully rewritten each call
    float* out = (float*)d_out;                // {total, total_ce, total_dep}

    ce_rows_kernel<<<4 * NB, 256, 0, stream>>>(o0, o1, o2, o3, targets, nll);
    finalize_kernel<<<1, 1024, 0, stream>>>(nll, p0, p1, p2, p3, v01, v12, v23, out);
}

// Round 2
// 297.969 us; speedup vs baseline: 1.0343x; 1.0343x over previous
//
#include <hip/hip_runtime.h>
#include <float.h>

// HierarchicalLoss: total = 0.5*sum_l CE(out_l, targets[:,l]) + 0.5*sum_l (e-1)*mean(1-V_l[p_l,p_{l+1}])
// R2: one block per row, all 4 levels fused. Register-resident two-pass softmax:
// all float4 loads issued independently up front (MLP), then block max, then exps.

#define NB 4096

static constexpr float LOG2E = 1.4426950408889634f;
static constexpr float LN2   = 0.6931471805599453f;
static constexpr float E_M1  = 1.7182818284590452f;   // e - 1

__device__ __forceinline__ float wave_max(float v) {
    #pragma unroll
    for (int off = 32; off; off >>= 1) v = fmaxf(v, __shfl_xor(v, off));
    return v;
}
__device__ __forceinline__ float wave_sum(float v) {
    #pragma unroll
    for (int off = 32; off; off >>= 1) v += __shfl_xor(v, off);
    return v;
}
__device__ __forceinline__ float max4(float4 v) {
    return fmaxf(fmaxf(v.x, v.y), fmaxf(v.z, v.w));
}
__device__ __forceinline__ float sumexp4(float4 v, float M) {
    return exp2f((v.x - M) * LOG2E) + exp2f((v.y - M) * LOG2E)
         + exp2f((v.z - M) * LOG2E) + exp2f((v.w - M) * LOG2E);
}

// Block = 256 threads = 4 waves, one block per row.
// All waves: 1/4 of level-3 row (8 float4/lane).
// wave0 lanes<32: level-0 (1 float4/lane). wave1: level-1 (2 float4/lane).
// waves 2,3: level-2 (4 float4/lane).
__global__ __launch_bounds__(256) void ce_fused_kernel(
    const float* __restrict__ o0, const float* __restrict__ o1,
    const float* __restrict__ o2, const float* __restrict__ o3,
    const int* __restrict__ targets, float* __restrict__ nll)
{
    const int row  = blockIdx.x;
    const int tid  = threadIdx.x;
    const int wv   = tid >> 6;
    const int lane = tid & 63;

    // ---- issue ALL loads first (independent -> deep vmcnt pipeline) ----
    const float4* r3 = (const float4*)(o3 + (size_t)row * 8192);
    float4 v3[8];
    #pragma unroll
    for (int k = 0; k < 8; k++) v3[k] = r3[tid + (k << 8)];

    const float4* r0 = (const float4*)(o0 + (size_t)row * 128);
    const float4* r1 = (const float4*)(o1 + (size_t)row * 512);
    const float4* r2 = (const float4*)(o2 + (size_t)row * 2048);
    float4 vs[4];
    if (wv == 0) {
        if (lane < 32) vs[0] = r0[lane];
    } else if (wv == 1) {
        vs[0] = r1[lane];
        vs[1] = r1[lane + 64];
    } else {
        const int t2 = tid - 128;           // 0..127
        #pragma unroll
        for (int j = 0; j < 4; j++) vs[j] = r2[t2 + j * 128];
    }

    // target-logit loads (scalar; latency hides under the bulk loads)
    float xt_a = 0.0f, xt_b = 0.0f;
    if (tid == 0) {
        xt_a = o3[(size_t)row * 8192 + targets[row * 4 + 3]];
        xt_b = o0[(size_t)row * 128  + targets[row * 4 + 0]];
    } else if (tid == 64) {
        xt_a = o1[(size_t)row * 512  + targets[row * 4 + 1]];
    } else if (tid == 128) {
        xt_a = o2[(size_t)row * 2048 + targets[row * 4 + 2]];
    }

    __shared__ float lm3[4], lm2[2], ls3[4], ls2[2];

    // ---- pass 1: maxes ----
    float m3 = -FLT_MAX;
    #pragma unroll
    for (int k = 0; k < 8; k++) m3 = fmaxf(m3, max4(v3[k]));
    m3 = wave_max(m3);

    float msml = -FLT_MAX;                  // per-wave small-level max
    if (wv == 0) {
        if (lane < 32) msml = max4(vs[0]);
    } else if (wv == 1) {
        msml = fmaxf(max4(vs[0]), max4(vs[1]));
    } else {
        #pragma unroll
        for (int j = 0; j < 4; j++) msml = fmaxf(msml, max4(vs[j]));
    }
    msml = wave_max(msml);                  // M0 in wave0, M1 in wave1, partial M2 in waves 2,3

    if (lane == 0) {
        lm3[wv] = m3;
        if (wv >= 2) lm2[wv - 2] = msml;
    }
    __syncthreads();

    const float M3 = fmaxf(fmaxf(lm3[0], lm3[1]), fmaxf(lm3[2], lm3[3]));
    const float M2 = (wv >= 2) ? fmaxf(lm2[0], lm2[1]) : 0.0f;

    // ---- pass 2: sum of exps (register-resident, no re-read) ----
    float s3 = 0.0f;
    #pragma unroll
    for (int k = 0; k < 8; k++) s3 += sumexp4(v3[k], M3);
    s3 = wave_sum(s3);

    float ssml = 0.0f;
    if (wv == 0) {
        if (lane < 32) ssml = sumexp4(vs[0], msml);
    } else if (wv == 1) {
        ssml = sumexp4(vs[0], msml) + sumexp4(vs[1], msml);
    } else {
        #pragma unroll
        for (int j = 0; j < 4; j++) ssml += sumexp4(vs[j], M2);
    }
    ssml = wave_sum(ssml);

    if (lane == 0) {
        ls3[wv] = s3;
        if (wv >= 2) ls2[wv - 2] = ssml;
    }
    __syncthreads();

    // ---- emit per-row NLLs: nll[row*4 + lvl] (row-major for coalesced finalize) ----
    if (tid == 0) {
        const float S3 = ls3[0] + ls3[1] + ls3[2] + ls3[3];
        nll[row * 4 + 3] = M3 + log2f(S3) * LN2 - xt_a;
        nll[row * 4 + 0] = msml + log2f(ssml) * LN2 - xt_b;   // msml==M0, ssml==S0 here
    } else if (tid == 64) {
        nll[row * 4 + 1] = msml + log2f(ssml) * LN2 - xt_a;   // M1, S1
    } else if (tid == 128) {
        const float S2 = ls2[0] + ls2[1];
        nll[row * 4 + 2] = M2 + log2f(S2) * LN2 - xt_a;
    }
}

// Single block: reduce 4096x4 NLLs + 3x4096 validity gathers -> 3 scalars.
__global__ __launch_bounds__(1024) void finalize_kernel(
    const float* __restrict__ nll,
    const int* __restrict__ p0, const int* __restrict__ p1,
    const int* __restrict__ p2, const int* __restrict__ p3,
    const int* __restrict__ v01, const int* __restrict__ v12,
    const int* __restrict__ v23, float* __restrict__ out)
{
    const int tid = threadIdx.x;

    // per-level CE partials: nll is [row][4] -> float4 per row
    const float4* nr = (const float4*)nll;
    float c0 = 0.f, c1 = 0.f, c2 = 0.f, c3 = 0.f;
    #pragma unroll
    for (int j = 0; j < 4; j++) {
        float4 v = nr[tid + j * 1024];
        c0 += v.x; c1 += v.y; c2 += v.z; c3 += v.w;
    }

    // prefetch all pred indices (coalesced), then issue 12 independent gathers
    int a[4], b[4], c[4], d[4];
    #pragma unroll
    for (int j = 0; j < 4; j++) {
        const int i = tid + j * 1024;
        a[j] = p0[i]; b[j] = p1[i]; c[j] = p2[i]; d[j] = p3[i];
    }
    float ok0 = 0.f, ok1 = 0.f, ok2 = 0.f;
    #pragma unroll
    for (int j = 0; j < 4; j++) {
        ok0 += (v01[a[j] * 512  + b[j]] != 0) ? 1.f : 0.f;
        ok1 += (v12[b[j] * 2048 + c[j]] != 0) ? 1.f : 0.f;
        ok2 += (v23[c[j] * 8192 + d[j]] != 0) ? 1.f : 0.f;
    }

    // one-barrier block reduction of 7 values
    float vals[7] = {c0, c1, c2, c3, ok0, ok1, ok2};
    #pragma unroll
    for (int q = 0; q < 7; q++) {
        #pragma unroll
        for (int off = 32; off; off >>= 1) vals[q] += __shfl_xor(vals[q], off);
    }
    __shared__ float lds[16][7];
    if ((tid & 63) == 0) {
        #pragma unroll
        for (int q = 0; q < 7; q++) lds[tid >> 6][q] = vals[q];
    }
    __syncthreads();

    if (tid == 0) {
        float res[7];
        #pragma unroll
        for (int q = 0; q < 7; q++) {
            float t = 0.f;
            for (int w = 0; w < 16; w++) t += lds[w][q];
            res[q] = t;
        }
        const float inv_b = 1.0f / (float)NB;
        const float total_ce = (res[0] + res[1] + res[2] + res[3]) * inv_b;
        float total_dep = 0.f;
        #pragma unroll
        for (int q = 4; q < 7; q++)
            total_dep += E_M1 * (((float)NB - res[q]) * inv_b);
        out[0] = 0.5f * total_ce + 0.5f * total_dep;   // ALPHA = 0.5
        out[1] = total_ce;
        out[2] = total_dep;
    }
}

extern "C" void kernel_launch(void* const* d_in, const int* in_sizes, int n_in,
                              void* d_out, int out_size, void* d_ws, size_t ws_size,
                              hipStream_t stream)
{
    const float* o0 = (const float*)d_in[0];   // 4096x128
    const float* o1 = (const float*)d_in[1];   // 4096x512
    const float* o2 = (const float*)d_in[2];   // 4096x2048
    const float* o3 = (const float*)d_in[3];   // 4096x8192
    const int* targets = (const int*)d_in[4];  // 4096x4
    const int* p0 = (const int*)d_in[5];
    const int* p1 = (const int*)d_in[6];
    const int* p2 = (const int*)d_in[7];
    const int* p3 = (const int*)d_in[8];
    const int* v01 = (const int*)d_in[9];      // 128x512
    const int* v12 = (const int*)d_in[10];     // 512x2048
    const int* v23 = (const int*)d_in[11];     // 2048x8192

    float* nll = (float*)d_ws;                 // 4096x4 floats, fully rewritten each call
    float* out = (float*)d_out;                // {total, total_ce, total_dep}

    ce_fused_kernel<<<NB, 256, 0, stream>>>(o0, o1, o2, o3, targets, nll);
    finalize_kernel<<<1, 1024, 0, stream>>>(nll, p0, p1, p2, p3, v01, v12, v23, out);
}

// Round 3
// 296.801 us; speedup vs baseline: 1.0383x; 1.0039x over previous
//
#include <hip/hip_runtime.h>
#include <float.h>

// HierarchicalLoss: total = 0.5*sum_l CE(out_l, targets[:,l]) + 0.5*sum_l (e-1)*mean(1-V_l[p_l,p_{l+1}])
// R3: identical structure to R2, but hardware transcendentals:
// exp2f -> __builtin_amdgcn_exp2f (v_exp_f32), log2f -> __builtin_amdgcn_logf (v_log_f32).
// Without -ffast-math the libm calls expand to ~10-instr OCML sequences; that VALU
// bloat (45M exps) was serializing against the 178 MB stream.

#define NB 4096

static constexpr float LOG2E = 1.4426950408889634f;
static constexpr float LN2   = 0.6931471805599453f;
static constexpr float E_M1  = 1.7182818284590452f;   // e - 1

__device__ __forceinline__ float hw_exp2(float x) { return __builtin_amdgcn_exp2f(x); }
__device__ __forceinline__ float hw_log2(float x) { return __builtin_amdgcn_logf(x); }

__device__ __forceinline__ float wave_max(float v) {
    #pragma unroll
    for (int off = 32; off; off >>= 1) v = fmaxf(v, __shfl_xor(v, off));
    return v;
}
__device__ __forceinline__ float wave_sum(float v) {
    #pragma unroll
    for (int off = 32; off; off >>= 1) v += __shfl_xor(v, off);
    return v;
}
__device__ __forceinline__ float max4(float4 v) {
    return fmaxf(fmaxf(v.x, v.y), fmaxf(v.z, v.w));
}
__device__ __forceinline__ float sumexp4(float4 v, float M) {
    return hw_exp2((v.x - M) * LOG2E) + hw_exp2((v.y - M) * LOG2E)
         + hw_exp2((v.z - M) * LOG2E) + hw_exp2((v.w - M) * LOG2E);
}

// Block = 256 threads = 4 waves, one block per row.
// All waves: 1/4 of level-3 row (8 float4/lane).
// wave0 lanes<32: level-0 (1 float4/lane). wave1: level-1 (2 float4/lane).
// waves 2,3: level-2 (4 float4/lane).
__global__ __launch_bounds__(256) void ce_fused_kernel(
    const float* __restrict__ o0, const float* __restrict__ o1,
    const float* __restrict__ o2, const float* __restrict__ o3,
    const int* __restrict__ targets, float* __restrict__ nll)
{
    const int row  = blockIdx.x;
    const int tid  = threadIdx.x;
    const int wv   = tid >> 6;
    const int lane = tid & 63;

    // ---- issue ALL loads first (independent -> deep vmcnt pipeline) ----
    const float4* r3 = (const float4*)(o3 + (size_t)row * 8192);
    float4 v3[8];
    #pragma unroll
    for (int k = 0; k < 8; k++) v3[k] = r3[tid + (k << 8)];

    const float4* r0 = (const float4*)(o0 + (size_t)row * 128);
    const float4* r1 = (const float4*)(o1 + (size_t)row * 512);
    const float4* r2 = (const float4*)(o2 + (size_t)row * 2048);
    float4 vs[4];
    if (wv == 0) {
        if (lane < 32) vs[0] = r0[lane];
    } else if (wv == 1) {
        vs[0] = r1[lane];
        vs[1] = r1[lane + 64];
    } else {
        const int t2 = tid - 128;           // 0..127
        #pragma unroll
        for (int j = 0; j < 4; j++) vs[j] = r2[t2 + j * 128];
    }

    // target-logit loads (scalar; latency hides under the bulk loads)
    float xt_a = 0.0f, xt_b = 0.0f;
    if (tid == 0) {
        xt_a = o3[(size_t)row * 8192 + targets[row * 4 + 3]];
        xt_b = o0[(size_t)row * 128  + targets[row * 4 + 0]];
    } else if (tid == 64) {
        xt_a = o1[(size_t)row * 512  + targets[row * 4 + 1]];
    } else if (tid == 128) {
        xt_a = o2[(size_t)row * 2048 + targets[row * 4 + 2]];
    }

    __shared__ float lm3[4], lm2[2], ls3[4], ls2[2];

    // ---- pass 1: maxes ----
    float m3 = -FLT_MAX;
    #pragma unroll
    for (int k = 0; k < 8; k++) m3 = fmaxf(m3, max4(v3[k]));
    m3 = wave_max(m3);

    float msml = -FLT_MAX;                  // per-wave small-level max
    if (wv == 0) {
        if (lane < 32) msml = max4(vs[0]);
    } else if (wv == 1) {
        msml = fmaxf(max4(vs[0]), max4(vs[1]));
    } else {
        #pragma unroll
        for (int j = 0; j < 4; j++) msml = fmaxf(msml, max4(vs[j]));
    }
    msml = wave_max(msml);                  // M0 in wave0, M1 in wave1, partial M2 in waves 2,3

    if (lane == 0) {
        lm3[wv] = m3;
        if (wv >= 2) lm2[wv - 2] = msml;
    }
    __syncthreads();

    const float M3 = fmaxf(fmaxf(lm3[0], lm3[1]), fmaxf(lm3[2], lm3[3]));
    const float M2 = (wv >= 2) ? fmaxf(lm2[0], lm2[1]) : 0.0f;

    // ---- pass 2: sum of exps (register-resident, no re-read) ----
    float s3 = 0.0f;
    #pragma unroll
    for (int k = 0; k < 8; k++) s3 += sumexp4(v3[k], M3);
    s3 = wave_sum(s3);

    float ssml = 0.0f;
    if (wv == 0) {
        if (lane < 32) ssml = sumexp4(vs[0], msml);
    } else if (wv == 1) {
        ssml = sumexp4(vs[0], msml) + sumexp4(vs[1], msml);
    } else {
        #pragma unroll
        for (int j = 0; j < 4; j++) ssml += sumexp4(vs[j], M2);
    }
    ssml = wave_sum(ssml);

    if (lane == 0) {
        ls3[wv] = s3;
        if (wv >= 2) ls2[wv - 2] = ssml;
    }
    __syncthreads();

    // ---- emit per-row NLLs: nll[row*4 + lvl] (row-major for coalesced finalize) ----
    if (tid == 0) {
        const float S3 = ls3[0] + ls3[1] + ls3[2] + ls3[3];
        nll[row * 4 + 3] = M3 + hw_log2(S3) * LN2 - xt_a;
        nll[row * 4 + 0] = msml + hw_log2(ssml) * LN2 - xt_b;   // msml==M0, ssml==S0 here
    } else if (tid == 64) {
        nll[row * 4 + 1] = msml + hw_log2(ssml) * LN2 - xt_a;   // M1, S1
    } else if (tid == 128) {
        const float S2 = ls2[0] + ls2[1];
        nll[row * 4 + 2] = M2 + hw_log2(S2) * LN2 - xt_a;
    }
}

// Single block: reduce 4096x4 NLLs + 3x4096 validity gathers -> 3 scalars.
__global__ __launch_bounds__(1024) void finalize_kernel(
    const float* __restrict__ nll,
    const int* __restrict__ p0, const int* __restrict__ p1,
    const int* __restrict__ p2, const int* __restrict__ p3,
    const int* __restrict__ v01, const int* __restrict__ v12,
    const int* __restrict__ v23, float* __restrict__ out)
{
    const int tid = threadIdx.x;

    // per-level CE partials: nll is [row][4] -> float4 per row
    const float4* nr = (const float4*)nll;
    float c0 = 0.f, c1 = 0.f, c2 = 0.f, c3 = 0.f;
    #pragma unroll
    for (int j = 0; j < 4; j++) {
        float4 v = nr[tid + j * 1024];
        c0 += v.x; c1 += v.y; c2 += v.z; c3 += v.w;
    }

    // prefetch all pred indices (coalesced), then issue 12 independent gathers
    int a[4], b[4], c[4], d[4];
    #pragma unroll
    for (int j = 0; j < 4; j++) {
        const int i = tid + j * 1024;
        a[j] = p0[i]; b[j] = p1[i]; c[j] = p2[i]; d[j] = p3[i];
    }
    float ok0 = 0.f, ok1 = 0.f, ok2 = 0.f;
    #pragma unroll
    for (int j = 0; j < 4; j++) {
        ok0 += (v01[a[j] * 512  + b[j]] != 0) ? 1.f : 0.f;
        ok1 += (v12[b[j] * 2048 + c[j]] != 0) ? 1.f : 0.f;
        ok2 += (v23[c[j] * 8192 + d[j]] != 0) ? 1.f : 0.f;
    }

    // one-barrier block reduction of 7 values
    float vals[7] = {c0, c1, c2, c3, ok0, ok1, ok2};
    #pragma unroll
    for (int q = 0; q < 7; q++) {
        #pragma unroll
        for (int off = 32; off; off >>= 1) vals[q] += __shfl_xor(vals[q], off);
    }
    __shared__ float lds[16][7];
    if ((tid & 63) == 0) {
        #pragma unroll
        for (int q = 0; q < 7; q++) lds[tid >> 6][q] = vals[q];
    }
    __syncthreads();

    if (tid == 0) {
        float res[7];
        #pragma unroll
        for (int q = 0; q < 7; q++) {
            float t = 0.f;
            for (int w = 0; w < 16; w++) t += lds[w][q];
            res[q] = t;
        }
        const float inv_b = 1.0f / (float)NB;
        const float total_ce = (res[0] + res[1] + res[2] + res[3]) * inv_b;
        float total_dep = 0.f;
        #pragma unroll
        for (int q = 4; q < 7; q++)
            total_dep += E_M1 * (((float)NB - res[q]) * inv_b);
        out[0] = 0.5f * total_ce + 0.5f * total_dep;   // ALPHA = 0.5
        out[1] = total_ce;
        out[2] = total_dep;
    }
}

extern "C" void kernel_launch(void* const* d_in, const int* in_sizes, int n_in,
                              void* d_out, int out_size, void* d_ws, size_t ws_size,
                              hipStream_t stream)
{
    const float* o0 = (const float*)d_in[0];   // 4096x128
    const float* o1 = (const float*)d_in[1];   // 4096x512
    const float* o2 = (const float*)d_in[2];   // 4096x2048
    const float* o3 = (const float*)d_in[3];   // 4096x8192
    const int* targets = (const int*)d_in[4];  // 4096x4
    const int* p0 = (const int*)d_in[5];
    const int* p1 = (const int*)d_in[6];
    const int* p2 = (const int*)d_in[7];
    const int* p3 = (const int*)d_in[8];
    const int* v01 = (const int*)d_in[9];      // 128x512
    const int* v12 = (const int*)d_in[10];     // 512x2048
    const int* v23 = (const int*)d_in[11];     // 2048x8192

    float* nll = (float*)d_ws;                 // 4096x4 floats, fully rewritten each call
    float* out = (float*)d_out;                // {total, total_ce, total_dep}

    ce_fused_kernel<<<NB, 256, 0, stream>>>(o0, o1, o2, o3, targets, nll);
    finalize_kernel<<<1, 1024, 0, stream>>>(nll, p0, p1, p2, p3, v01, v12, v23, out);
}

// Round 4
// 269.504 us; speedup vs baseline: 1.1435x; 1.1013x over previous
//
#include <hip/hip_runtime.h>
#include <float.h>

// HierarchicalLoss: total = 0.5*sum_l CE(out_l, targets[:,l]) + 0.5*sum_l (e-1)*mean(1-V_l[p_l,p_{l+1}])
// R4: the 12K random validity gathers were latency-serialized on ONE CU in
// finalize (~50 us). Distribute them across the 4096 ce blocks (3 gathers per
// block, hidden under the logit stream); finalize becomes a trivial 128 KB
// contiguous reduction.

#define NB 4096

static constexpr float LOG2E = 1.4426950408889634f;
static constexpr float LN2   = 0.6931471805599453f;
static constexpr float E_M1  = 1.7182818284590452f;   // e - 1

__device__ __forceinline__ float hw_exp2(float x) { return __builtin_amdgcn_exp2f(x); }
__device__ __forceinline__ float hw_log2(float x) { return __builtin_amdgcn_logf(x); }

__device__ __forceinline__ float wave_max(float v) {
    #pragma unroll
    for (int off = 32; off; off >>= 1) v = fmaxf(v, __shfl_xor(v, off));
    return v;
}
__device__ __forceinline__ float wave_sum(float v) {
    #pragma unroll
    for (int off = 32; off; off >>= 1) v += __shfl_xor(v, off);
    return v;
}
__device__ __forceinline__ float max4(float4 v) {
    return fmaxf(fmaxf(v.x, v.y), fmaxf(v.z, v.w));
}
__device__ __forceinline__ float sumexp4(float4 v, float M) {
    return hw_exp2((v.x - M) * LOG2E) + hw_exp2((v.y - M) * LOG2E)
         + hw_exp2((v.z - M) * LOG2E) + hw_exp2((v.w - M) * LOG2E);
}

// Block = 256 threads = 4 waves, one block per row. ws layout: [row][8] floats
// = {nll0, nll1, nll2, nll3, ok01, ok12, ok23, pad}.
__global__ __launch_bounds__(256) void ce_fused_kernel(
    const float* __restrict__ o0, const float* __restrict__ o1,
    const float* __restrict__ o2, const float* __restrict__ o3,
    const int* __restrict__ targets,
    const int* __restrict__ p0, const int* __restrict__ p1,
    const int* __restrict__ p2, const int* __restrict__ p3,
    const int* __restrict__ v01, const int* __restrict__ v12,
    const int* __restrict__ v23, float* __restrict__ ws8)
{
    const int row  = blockIdx.x;
    const int tid  = threadIdx.x;
    const int wv   = tid >> 6;
    const int lane = tid & 63;

    // ---- dependency-loss gathers: start the dependent chain FIRST ----
    int ia = 0, ib = 0, ic = 0, id = 0;
    if (tid == 192) {
        ia = p0[row]; ib = p1[row]; ic = p2[row]; id = p3[row];
    }

    // ---- issue ALL logit loads (independent -> deep vmcnt pipeline) ----
    const float4* r3 = (const float4*)(o3 + (size_t)row * 8192);
    float4 v3[8];
    #pragma unroll
    for (int k = 0; k < 8; k++) v3[k] = r3[tid + (k << 8)];

    const float4* r0 = (const float4*)(o0 + (size_t)row * 128);
    const float4* r1 = (const float4*)(o1 + (size_t)row * 512);
    const float4* r2 = (const float4*)(o2 + (size_t)row * 2048);
    float4 vs[4];
    if (wv == 0) {
        if (lane < 32) vs[0] = r0[lane];
    } else if (wv == 1) {
        vs[0] = r1[lane];
        vs[1] = r1[lane + 64];
    } else {
        const int t2 = tid - 128;           // 0..127
        #pragma unroll
        for (int j = 0; j < 4; j++) vs[j] = r2[t2 + j * 128];
    }

    // second round of the gather chain (independent scattered loads)
    if (tid == 192) {
        const float ok0 = (v01[ia * 512  + ib] != 0) ? 1.f : 0.f;
        const float ok1 = (v12[ib * 2048 + ic] != 0) ? 1.f : 0.f;
        const float ok2 = (v23[ic * 8192 + id] != 0) ? 1.f : 0.f;
        ws8[row * 8 + 4] = ok0;
        ws8[row * 8 + 5] = ok1;
        ws8[row * 8 + 6] = ok2;
    }

    // target-logit loads (scalar; latency hides under the bulk loads)
    float xt_a = 0.0f, xt_b = 0.0f;
    if (tid == 0) {
        xt_a = o3[(size_t)row * 8192 + targets[row * 4 + 3]];
        xt_b = o0[(size_t)row * 128  + targets[row * 4 + 0]];
    } else if (tid == 64) {
        xt_a = o1[(size_t)row * 512  + targets[row * 4 + 1]];
    } else if (tid == 128) {
        xt_a = o2[(size_t)row * 2048 + targets[row * 4 + 2]];
    }

    __shared__ float lm3[4], lm2[2], ls3[4], ls2[2];

    // ---- pass 1: maxes ----
    float m3 = -FLT_MAX;
    #pragma unroll
    for (int k = 0; k < 8; k++) m3 = fmaxf(m3, max4(v3[k]));
    m3 = wave_max(m3);

    float msml = -FLT_MAX;                  // per-wave small-level max
    if (wv == 0) {
        if (lane < 32) msml = max4(vs[0]);
    } else if (wv == 1) {
        msml = fmaxf(max4(vs[0]), max4(vs[1]));
    } else {
        #pragma unroll
        for (int j = 0; j < 4; j++) msml = fmaxf(msml, max4(vs[j]));
    }
    msml = wave_max(msml);                  // M0 in wave0, M1 in wave1, partial M2 in waves 2,3

    if (lane == 0) {
        lm3[wv] = m3;
        if (wv >= 2) lm2[wv - 2] = msml;
    }
    __syncthreads();

    const float M3 = fmaxf(fmaxf(lm3[0], lm3[1]), fmaxf(lm3[2], lm3[3]));
    const float M2 = (wv >= 2) ? fmaxf(lm2[0], lm2[1]) : 0.0f;

    // ---- pass 2: sum of exps (register-resident, no re-read) ----
    float s3 = 0.0f;
    #pragma unroll
    for (int k = 0; k < 8; k++) s3 += sumexp4(v3[k], M3);
    s3 = wave_sum(s3);

    float ssml = 0.0f;
    if (wv == 0) {
        if (lane < 32) ssml = sumexp4(vs[0], msml);
    } else if (wv == 1) {
        ssml = sumexp4(vs[0], msml) + sumexp4(vs[1], msml);
    } else {
        #pragma unroll
        for (int j = 0; j < 4; j++) ssml += sumexp4(vs[j], M2);
    }
    ssml = wave_sum(ssml);

    if (lane == 0) {
        ls3[wv] = s3;
        if (wv >= 2) ls2[wv - 2] = ssml;
    }
    __syncthreads();

    // ---- emit per-row NLLs ----
    if (tid == 0) {
        const float S3 = ls3[0] + ls3[1] + ls3[2] + ls3[3];
        ws8[row * 8 + 3] = M3 + hw_log2(S3) * LN2 - xt_a;
        ws8[row * 8 + 0] = msml + hw_log2(ssml) * LN2 - xt_b;   // M0, S0
    } else if (tid == 64) {
        ws8[row * 8 + 1] = msml + hw_log2(ssml) * LN2 - xt_a;   // M1, S1
    } else if (tid == 128) {
        const float S2 = ls2[0] + ls2[1];
        ws8[row * 8 + 2] = M2 + hw_log2(S2) * LN2 - xt_a;
    }
}

// Single block: reduce 4096x8 contiguous floats -> 3 scalars. ~128 KB, few us.
__global__ __launch_bounds__(1024) void finalize_kernel(
    const float* __restrict__ ws8, float* __restrict__ out)
{
    const int tid = threadIdx.x;
    const float4* w4 = (const float4*)ws8;

    float c0 = 0.f, c1 = 0.f, c2 = 0.f, c3 = 0.f;
    float ok0 = 0.f, ok1 = 0.f, ok2 = 0.f;
    #pragma unroll
    for (int j = 0; j < 4; j++) {
        const int row = tid + j * 1024;
        float4 a = w4[row * 2];        // nll0..3
        float4 b = w4[row * 2 + 1];    // ok01, ok12, ok23, pad
        c0 += a.x; c1 += a.y; c2 += a.z; c3 += a.w;
        ok0 += b.x; ok1 += b.y; ok2 += b.z;
    }

    float vals[7] = {c0, c1, c2, c3, ok0, ok1, ok2};
    #pragma unroll
    for (int q = 0; q < 7; q++) {
        #pragma unroll
        for (int off = 32; off; off >>= 1) vals[q] += __shfl_xor(vals[q], off);
    }
    __shared__ float lds[16][7];
    if ((tid & 63) == 0) {
        #pragma unroll
        for (int q = 0; q < 7; q++) lds[tid >> 6][q] = vals[q];
    }
    __syncthreads();

    if (tid == 0) {
        float res[7];
        #pragma unroll
        for (int q = 0; q < 7; q++) {
            float t = 0.f;
            for (int w = 0; w < 16; w++) t += lds[w][q];
            res[q] = t;
        }
        const float inv_b = 1.0f / (float)NB;
        const float total_ce = (res[0] + res[1] + res[2] + res[3]) * inv_b;
        float total_dep = 0.f;
        #pragma unroll
        for (int q = 4; q < 7; q++)
            total_dep += E_M1 * (((float)NB - res[q]) * inv_b);
        out[0] = 0.5f * total_ce + 0.5f * total_dep;   // ALPHA = 0.5
        out[1] = total_ce;
        out[2] = total_dep;
    }
}

extern "C" void kernel_launch(void* const* d_in, const int* in_sizes, int n_in,
                              void* d_out, int out_size, void* d_ws, size_t ws_size,
                              hipStream_t stream)
{
    const float* o0 = (const float*)d_in[0];   // 4096x128
    const float* o1 = (const float*)d_in[1];   // 4096x512
    const float* o2 = (const float*)d_in[2];   // 4096x2048
    const float* o3 = (const float*)d_in[3];   // 4096x8192
    const int* targets = (const int*)d_in[4];  // 4096x4
    const int* p0 = (const int*)d_in[5];
    const int* p1 = (const int*)d_in[6];
    const int* p2 = (const int*)d_in[7];
    const int* p3 = (const int*)d_in[8];
    const int* v01 = (const int*)d_in[9];      // 128x512
    const int* v12 = (const int*)d_in[10];     // 512x2048
    const int* v23 = (const int*)d_in[11];     // 2048x8192

    float* ws8 = (float*)d_ws;                 // 4096x8 floats, fully rewritten each call
    float* out = (float*)d_out;                // {total, total_ce, total_dep}

    ce_fused_kernel<<<NB, 256, 0, stream>>>(o0, o1, o2, o3, targets,
                                            p0, p1, p2, p3, v01, v12, v23, ws8);
    finalize_kernel<<<1, 1024, 0, stream>>>(ws8, out);
}